// Round 2
// baseline (223.608 us; speedup 1.0000x reference)
//
#include <hip/hip_runtime.h>
#include <stdint.h>

// LIF -> 1x1conv(512->2048) -> BN -> LIF -> 1x1conv(2048->512) -> BN -> +x
// T=4 B=32 C=512 Ch=2048 HW=196. Split-hi/lo bf16 W1 (fp32-exact spike
// decisions), plain bf16 W2. This round: 8-phase counted-vmcnt schedule
// (T2+T3+T4+T5) on both GEMMs.

typedef __bf16 bf16x8 __attribute__((ext_vector_type(8)));
typedef float f32x4 __attribute__((ext_vector_type(4)));
typedef float f32x2 __attribute__((ext_vector_type(2)));

#define TPLANE 3211264u     // B*C*HW
#define NCOL   6272u        // B*HW
#define MFMA_BF16 __builtin_amdgcn_mfma_f32_16x16x32_bf16

#define BAR()  __builtin_amdgcn_s_barrier()
#define BARL() do { __builtin_amdgcn_s_barrier(); \
                    asm volatile("s_waitcnt lgkmcnt(0)" ::: "memory"); } while (0)
#define VMW(n) asm volatile("s_waitcnt vmcnt(" #n ")" ::: "memory")

static __device__ __forceinline__ uint16_t f2bf(float f) {
  union { float f; uint32_t u; } v; v.f = f;
  return (uint16_t)((v.u + 0x7FFFu + ((v.u >> 16) & 1u)) >> 16);  // RNE
}
static __device__ __forceinline__ float bf2f(uint16_t h) {
  union { uint32_t u; float f; } v; v.u = ((uint32_t)h) << 16;
  return v.f;
}
static __device__ __forceinline__ void async16(const void* g, void* l) {
  __builtin_amdgcn_global_load_lds((const __attribute__((address_space(1))) uint32_t*)g,
                                   (__attribute__((address_space(3))) uint32_t*)l, 16, 0, 0);
}

// ---------------------------------------------------------------------------
__global__ void prep_kernel(const float* __restrict__ W1, const float* __restrict__ W2,
                            const float* __restrict__ g1, const float* __restrict__ b1,
                            const float* __restrict__ m1, const float* __restrict__ v1,
                            const float* __restrict__ g2, const float* __restrict__ b2,
                            const float* __restrict__ m2, const float* __restrict__ v2,
                            uint16_t* __restrict__ Ws, uint16_t* __restrict__ W2b,
                            float* __restrict__ scale1, float* __restrict__ bias1,
                            float* __restrict__ scale2, float* __restrict__ bias2) {
  uint32_t i = blockIdx.x * 512u + threadIdx.x;
  uint32_t o = i >> 9, c = i & 511u;
  float w = W1[i];
  uint16_t hi = f2bf(w);
  uint16_t lo = f2bf(w - bf2f(hi));
  Ws[(size_t)(2u * o) * 512u + c] = hi;
  Ws[(size_t)(2u * o + 1u) * 512u + c] = lo;
  W2b[i] = f2bf(W2[i]);
  if (i < 2048u) { float s = g1[i] / sqrtf(v1[i] + 1e-5f); scale1[i] = s; bias1[i] = b1[i] - m1[i] * s; }
  if (i < 512u)  { float s = g2[i] / sqrtf(v2[i] + 1e-5f); scale2[i] = s; bias2[i] = b2[i] - m2[i] * s; }
}

// ---------------------------------------------------------------------------
// LIF over input (bit-exact fp32), spikes bf16 in K-blocked layout:
// chunk = (cblk*4 + t)*NCOL + n, 16B per chunk (8 channels).
__global__ void lif1_kernel(const float* __restrict__ x, uint16_t* __restrict__ s1) {
  __shared__ __align__(16) uint16_t sl[64 * 66 * 4];
  const uint32_t tid = threadIdx.x;
  const uint32_t c0 = blockIdx.x * 64u;
  const uint32_t n0 = blockIdx.y * 64u;
  #pragma unroll
  for (int j = 0; j < 16; ++j) {
    uint32_t idx = (uint32_t)j * 256u + tid;
    uint32_t cl = idx >> 6, nl = idx & 63u;
    uint32_t n = n0 + nl;
    uint32_t b = n / 196u, hw = n - b * 196u;
    const float* px = x + (size_t)(b * 512u + c0 + cl) * 196u + hw;
    float v = 0.f;
    uint16_t sp[4];
    #pragma unroll
    for (int t = 0; t < 4; ++t) {
      float xv = px[(size_t)t * TPLANE];
      v += (xv - v) * 0.5f;
      bool s = (v >= 1.0f);
      sp[t] = s ? (uint16_t)0x3F80u : (uint16_t)0u;
      v = s ? 0.f : v;
    }
    uint2 pk;
    pk.x = (uint32_t)sp[0] | ((uint32_t)sp[1] << 16);
    pk.y = (uint32_t)sp[2] | ((uint32_t)sp[3] << 16);
    *(uint2*)&sl[(cl * 66u + nl) * 4u] = pk;
  }
  __syncthreads();
  #pragma unroll
  for (int j = 0; j < 8; ++j) {
    uint32_t id = (uint32_t)j * 256u + tid;
    uint32_t nl = id & 63u, t = (id >> 6) & 3u, cb = id >> 8;
    uint32_t us[4];
    #pragma unroll
    for (int e = 0; e < 4; ++e) {
      uint32_t lo16 = sl[((cb * 8u + 2u * e) * 66u + nl) * 4u + t];
      uint32_t hi16 = sl[((cb * 8u + 2u * e + 1u) * 66u + nl) * 4u + t];
      us[e] = lo16 | (hi16 << 16);
    }
    uint32_t chunk = (((c0 >> 3) + cb) * 4u + t) * NCOL + n0 + nl;
    uint4 o4; o4.x = us[0]; o4.y = us[1]; o4.z = us[2]; o4.w = us[3];
    *(uint4*)(s1 + (size_t)chunk * 8u) = o4;
  }
}

// ---------------------------------------------------------------------------
// GEMM1: M'=4096 (hi/lo rows), K=512, N-strip = 64n x 4t (256 cols).
// 8-phase deep pipeline, dbuf 128KB LDS, counted vmcnt, setprio, fused
// BN1 + in-register LIF2 scan -> s2 spikes.
__launch_bounds__(512, 2)
__global__ void gemm1_lif2_kernel(const uint16_t* __restrict__ Ws,
                                  const uint16_t* __restrict__ s1,
                                  const float* __restrict__ scale1,
                                  const float* __restrict__ bias1,
                                  uint16_t* __restrict__ s2) {
  extern __shared__ __align__(16) char lds[];   // [buf:2][A 32KB][B 32KB]
  const uint32_t tid = threadIdx.x;
  const uint32_t wid = tid >> 6, lane = tid & 63u;
  const uint32_t il = lane & 15u, g = lane >> 4;
  const uint32_t wm = wid >> 2, wn = wid & 3u;
  const uint32_t m0 = blockIdx.x * 256u;
  const uint32_t n0 = blockIdx.y * 64u;
  const char* WsC = (const char*)Ws;
  const char* s1C = (const char*)s1;

  // staging lane constants (A: [i:256][q:8] chunks, src pre-swizzled)
  const uint32_t ia = tid >> 3;
  const uint32_t qg = (tid & 7u) ^ (ia & 7u);
  const uint32_t aSrc = (m0 + ia) * 1024u + qg * 16u;
  // B: [kb:8][ (n4*4+t)*16+nl ] chunks
  const uint32_t kbl = tid >> 8, colb = tid & 255u;
  const uint32_t bn4 = colb >> 6, bt = (colb >> 4) & 3u, bnl = colb & 15u;
  const uint32_t bSrc = ((kbl * 4u + bt) * NCOL + n0 + bn4 * 16u + bnl) * 16u;

  // ds-read lane constants
  const uint32_t aRd = (wm * 128u + il) * 128u + ((g ^ (il & 7u)) * 16u);
  const uint32_t bRd = g * 4096u + wn * 1024u + il * 16u;

  f32x4 acc[8][4];
  #pragma unroll
  for (int i = 0; i < 8; ++i)
    #pragma unroll
    for (int j = 0; j < 4; ++j) acc[i][j] = (f32x4){0.f, 0.f, 0.f, 0.f};
  bf16x8 af[8], bf0, bf1;

#define G1_SA(ga, kn) async16(WsC + (aSrc + (ga)*65536u + (kn)*128u), \
      lds + (nxt)*65536u + (ga)*8192u + wid*1024u)
#define G1_SB(gb, kn) async16(s1C + (bSrc + (gb)*802816u + (kn)*3211264u), \
      lds + (nxt)*65536u + 32768u + (gb)*8192u + wid*1024u)
#define G1_RDA(ks) do { _Pragma("unroll") for (int fm = 0; fm < 8; ++fm) \
    af[fm] = *(const bf16x8*)(Ac + ((aRd ^ ((ks) << 6)) + (uint32_t)fm * 2048u)); } while (0)
#define G1_RDB(ks, th) do { \
    bf0 = *(const bf16x8*)(Bc + (bRd + (th)*512u + (ks)*16384u)); \
    bf1 = *(const bf16x8*)(Bc + (bRd + (th)*512u + 256u + (ks)*16384u)); } while (0)
#define G1_MFMA(th) do { __builtin_amdgcn_s_setprio(1); \
  _Pragma("unroll") for (int fm = 0; fm < 8; ++fm) { \
    acc[fm][(th)*2]   = MFMA_BF16(af[fm], bf0, acc[fm][(th)*2], 0, 0, 0); \
    acc[fm][(th)*2+1] = MFMA_BF16(af[fm], bf1, acc[fm][(th)*2+1], 0, 0, 0); } \
  __builtin_amdgcn_s_setprio(0); } while (0)

  // prologue: stage tile 0 fully (order A0..A3,B0..B3)
  {
    const uint32_t nxt = 0u;
    G1_SA(0, 0u); G1_SA(1, 0u); G1_SA(2, 0u); G1_SA(3, 0u);
    G1_SB(0, 0u); G1_SB(1, 0u); G1_SB(2, 0u); G1_SB(3, 0u);
  }
  VMW(2);     // first 6 groups (A all + B kb0-3) done; B kb4-7 in flight
  BAR();

  for (uint32_t kt = 0; kt < 7u; ++kt) {
    const uint32_t cur = kt & 1u, nxt = cur ^ 1u, kn = kt + 1u;
    const char* Ac = lds + cur * 65536u;
    const char* Bc = Ac + 32768u;
    // P0: reads(A ks0 + B t01 ks0) | stage A01(k+1)
    G1_RDA(0u); G1_RDB(0u, 0u);
    G1_SA(0, kn); G1_SA(1, kn);
    BARL(); G1_MFMA(0); BAR();
    // P1: reads(B t23 ks0) | stage A23(k+1) | wait Bq1(k)
    G1_RDB(0u, 1u);
    G1_SA(2, kn); G1_SA(3, kn);
    VMW(4);
    BARL(); G1_MFMA(1); BAR();
    // P2: reads(A ks1 + B t01 ks1) | stage B01(k+1)
    G1_RDA(1u); G1_RDB(1u, 0u);
    G1_SB(0, kn); G1_SB(1, kn);
    BARL(); G1_MFMA(0); BAR();
    // P3: reads(B t23 ks1) | stage B23(k+1) | wait first-6(k+1)
    G1_RDB(1u, 1u);
    G1_SB(2, kn); G1_SB(3, kn);
    VMW(2);
    BARL(); G1_MFMA(1); BAR();
  }
  { // peeled last tile (kt=7, cur=1), drains
    const char* Ac = lds + 65536u;
    const char* Bc = Ac + 32768u;
    G1_RDA(0u); G1_RDB(0u, 0u); BARL(); G1_MFMA(0); BAR();
    G1_RDB(0u, 1u); VMW(0);     BARL(); G1_MFMA(1); BAR();
    G1_RDA(1u); G1_RDB(1u, 0u); BARL(); G1_MFMA(0); BAR();
    G1_RDB(1u, 1u);             BARL(); G1_MFMA(1);
  }
#undef G1_SA
#undef G1_SB
#undef G1_RDA
#undef G1_RDB
#undef G1_MFMA

  // epilogue: hi+lo combine, BN1, in-register LIF2 scan, scatter s2
  const uint32_t n = n0 + wn * 16u + il;
  #pragma unroll
  for (int fm = 0; fm < 8; ++fm) {
    uint32_t oo = (m0 >> 1) + wm * 64u + (uint32_t)fm * 8u + 2u * g;
    f32x2 sc = *(const f32x2*)&scale1[oo];
    f32x2 bi = *(const f32x2*)&bias1[oo];
    float v0 = 0.f, v1 = 0.f;
    uint32_t outw[4];
    #pragma unroll
    for (int t = 0; t < 4; ++t) {
      float hb0 = (acc[fm][t][0] + acc[fm][t][1]) * sc[0] + bi[0];
      float hb1 = (acc[fm][t][2] + acc[fm][t][3]) * sc[1] + bi[1];
      v0 += (hb0 - v0) * 0.5f; bool s0 = (v0 >= 1.0f); v0 = s0 ? 0.f : v0;
      v1 += (hb1 - v1) * 0.5f; bool s1v = (v1 >= 1.0f); v1 = s1v ? 0.f : v1;
      outw[t] = (s0 ? 0x3F80u : 0u) | (s1v ? 0x3F800000u : 0u);
    }
    #pragma unroll
    for (int t = 0; t < 4; ++t) {
      size_t off = (size_t)(((oo >> 3) * 4u + (uint32_t)t) * NCOL + n) * 16u + (size_t)((oo & 7u) * 2u);
      *(uint32_t*)((char*)s2 + off) = outw[t];
    }
  }
}

// ---------------------------------------------------------------------------
// GEMM2: M=512, K=2048, same 8-phase pipeline at 128M x (64n x 4t).
// dbuf 96KB LDS; fused BN2 + residual + LDS-transpose float4 stores.
__launch_bounds__(512, 2)
__global__ void gemm2_out_kernel(const uint16_t* __restrict__ W2b,
                                 const uint16_t* __restrict__ s2,
                                 const float* __restrict__ scale2,
                                 const float* __restrict__ bias2,
                                 const float* __restrict__ xin,
                                 float* __restrict__ outp) {
  extern __shared__ __align__(16) char lds[];   // [buf:2][A 16KB][B 32KB]
  const uint32_t tid = threadIdx.x;
  const uint32_t wid = tid >> 6, lane = tid & 63u;
  const uint32_t il = lane & 15u, g = lane >> 4;
  const uint32_t wm = wid >> 2, wn = wid & 3u;
  const uint32_t m0 = blockIdx.x * 128u;
  const uint32_t n0 = blockIdx.y * 64u;
  const char* W2C = (const char*)W2b;
  const char* s2C = (const char*)s2;

  const uint32_t ia = tid >> 3;                 // 0..63 rows per A group
  const uint32_t qg = (tid & 7u) ^ (ia & 7u);
  const uint32_t aSrc = (m0 + ia) * 4096u + qg * 16u;
  const uint32_t kbl = tid >> 8, colb = tid & 255u;
  const uint32_t bn4 = colb >> 6, bt = (colb >> 4) & 3u, bnl = colb & 15u;
  const uint32_t bSrc = ((kbl * 4u + bt) * NCOL + n0 + bn4 * 16u + bnl) * 16u;

  const uint32_t aRd = (wm * 64u + il) * 128u + ((g ^ (il & 7u)) * 16u);
  const uint32_t bRd = g * 4096u + wn * 1024u + il * 16u;

  f32x4 acc[4][4];
  #pragma unroll
  for (int i = 0; i < 4; ++i)
    #pragma unroll
    for (int j = 0; j < 4; ++j) acc[i][j] = (f32x4){0.f, 0.f, 0.f, 0.f};
  bf16x8 af[4], bf0, bf1;

#define G2_SA(ga, kn) async16(W2C + (aSrc + (ga)*262144u + (kn)*128u), \
      lds + (nxt)*49152u + (ga)*8192u + wid*1024u)
#define G2_SB(gb, kn) async16(s2C + (bSrc + (gb)*802816u + (kn)*3211264u), \
      lds + (nxt)*49152u + 16384u + (gb)*8192u + wid*1024u)
#define G2_RDA(ks) do { _Pragma("unroll") for (int fm = 0; fm < 4; ++fm) \
    af[fm] = *(const bf16x8*)(Ac + ((aRd ^ ((ks) << 6)) + (uint32_t)fm * 2048u)); } while (0)
#define G2_RDB(ks, th) do { \
    bf0 = *(const bf16x8*)(Bc + (bRd + (th)*512u + (ks)*16384u)); \
    bf1 = *(const bf16x8*)(Bc + (bRd + (th)*512u + 256u + (ks)*16384u)); } while (0)
#define G2_MFMA(th) do { __builtin_amdgcn_s_setprio(1); \
  _Pragma("unroll") for (int fm = 0; fm < 4; ++fm) { \
    acc[fm][(th)*2]   = MFMA_BF16(af[fm], bf0, acc[fm][(th)*2], 0, 0, 0); \
    acc[fm][(th)*2+1] = MFMA_BF16(af[fm], bf1, acc[fm][(th)*2+1], 0, 0, 0); } \
  __builtin_amdgcn_s_setprio(0); } while (0)

  // prologue: stage tile 0 (order A0,A1,B0,B1,B2,B3)
  {
    const uint32_t nxt = 0u;
    G2_SA(0, 0u); G2_SA(1, 0u);
    G2_SB(0, 0u); G2_SB(1, 0u); G2_SB(2, 0u); G2_SB(3, 0u);
  }
  VMW(2);     // first 4 groups done; B kb4-7 in flight
  BAR();

  for (uint32_t kt = 0; kt < 31u; ++kt) {
    const uint32_t cur = kt & 1u, nxt = cur ^ 1u, kn = kt + 1u;
    const char* Ac = lds + cur * 49152u;
    const char* Bc = Ac + 16384u;
    // P0
    G2_RDA(0u); G2_RDB(0u, 0u);
    G2_SA(0, kn); G2_SA(1, kn);
    BARL(); G2_MFMA(0); BAR();
    // P1: wait Bq1(k)
    G2_RDB(0u, 1u);
    G2_SB(0, kn);
    VMW(3);
    BARL(); G2_MFMA(1); BAR();
    // P2
    G2_RDA(1u); G2_RDB(1u, 0u);
    G2_SB(1, kn);
    BARL(); G2_MFMA(0); BAR();
    // P3: wait first-4(k+1)
    G2_RDB(1u, 1u);
    G2_SB(2, kn); G2_SB(3, kn);
    VMW(2);
    BARL(); G2_MFMA(1); BAR();
  }
  { // peeled last tile (kt=31, cur=1)
    const char* Ac = lds + 49152u;
    const char* Bc = Ac + 16384u;
    G2_RDA(0u); G2_RDB(0u, 0u); BARL(); G2_MFMA(0); BAR();
    G2_RDB(0u, 1u); VMW(0);     BARL(); G2_MFMA(1); BAR();
    G2_RDA(1u); G2_RDB(1u, 0u); BARL(); G2_MFMA(0); BAR();
    G2_RDB(1u, 1u);             BARL(); G2_MFMA(1); BAR();
  }
#undef G2_SA
#undef G2_SB
#undef G2_RDA
#undef G2_RDB
#undef G2_MFMA

  // epilogue: BN2 + residual, LDS transpose -> float4 stores (proven pattern)
  float* ep = (float*)lds;
  const uint32_t cl = lane >> 2, qq = lane & 3u;
  #pragma unroll
  for (int fm = 0; fm < 4; ++fm) {
    const uint32_t cbase = m0 + wm * 64u + (uint32_t)fm * 16u;
    f32x4 sc = *(const f32x4*)&scale2[cbase + 4u * g];
    f32x4 bi = *(const f32x4*)&bias2[cbase + 4u * g];
    #pragma unroll
    for (int t = 0; t < 4; ++t)
      #pragma unroll
      for (int r = 0; r < 4; ++r)
        ep[wid * 1280u + ((4u * g + (uint32_t)r) * 4u + (uint32_t)t) * 20u + il]
            = acc[fm][t][r] * sc[r] + bi[r];
    __syncthreads();
    #pragma unroll
    for (int t = 0; t < 4; ++t) {
      f32x4 val = *(const f32x4*)&ep[wid * 1280u + (cl * 4u + (uint32_t)t) * 20u + qq * 4u];
      uint32_t nn = n0 + wn * 16u + qq * 4u;
      uint32_t b = nn / 196u, hw = nn - b * 196u;
      uint32_t c = cbase + cl;
      size_t off = (((size_t)t * 32u + b) * 512u + c) * 196u + hw;
      f32x4 iv = *(const f32x4*)(xin + off);
      *(f32x4*)(outp + off) = val + iv;
    }
    __syncthreads();
  }
}

// ---------------------------------------------------------------------------
extern "C" void kernel_launch(void* const* d_in, const int* in_sizes, int n_in,
                              void* d_out, int out_size, void* d_ws, size_t ws_size,
                              hipStream_t stream) {
  const float* x  = (const float*)d_in[0];
  const float* W1 = (const float*)d_in[1];
  const float* g1 = (const float*)d_in[2];
  const float* b1 = (const float*)d_in[3];
  const float* m1 = (const float*)d_in[4];
  const float* v1 = (const float*)d_in[5];
  const float* W2 = (const float*)d_in[6];
  const float* g2 = (const float*)d_in[7];
  const float* b2 = (const float*)d_in[8];
  const float* m2 = (const float*)d_in[9];
  const float* v2 = (const float*)d_in[10];
  float* out = (float*)d_out;
  char* ws = (char*)d_ws;

  uint16_t* s2b    = (uint16_t*)(ws);                    // 102,760,448 B
  uint16_t* s1b    = (uint16_t*)(ws + 102760448);        //  25,690,112 B
  uint16_t* Wsb    = (uint16_t*)(ws + 128450560);        //   4,194,304 B
  uint16_t* W2bb   = (uint16_t*)(ws + 132644864);        //   2,097,152 B
  float*    scale1 = (float*)(ws + 134742016);
  float*    bias1  = (float*)(ws + 134750208);
  float*    scale2 = (float*)(ws + 134758400);
  float*    bias2  = (float*)(ws + 134760448);

  hipFuncSetAttribute((const void*)gemm1_lif2_kernel,
                      hipFuncAttributeMaxDynamicSharedMemorySize, 131072);
  hipFuncSetAttribute((const void*)gemm2_out_kernel,
                      hipFuncAttributeMaxDynamicSharedMemorySize, 98304);

  prep_kernel<<<2048, 512, 0, stream>>>(W1, W2, g1, b1, m1, v1, g2, b2, m2, v2,
                                        Wsb, W2bb, scale1, bias1, scale2, bias2);
  lif1_kernel<<<dim3(8, 98), 256, 0, stream>>>(x, s1b);
  gemm1_lif2_kernel<<<dim3(16, 98), 512, 131072, stream>>>(Wsb, s1b, scale1, bias1, s2b);
  gemm2_out_kernel<<<dim3(4, 98), 512, 98304, stream>>>(W2bb, s2b, scale2, bias2, x, out);
}

// Round 4
// 201.873 us; speedup vs baseline: 1.1077x; 1.1077x over previous
//
#include <hip/hip_runtime.h>
#include <stdint.h>

// LIF -> 1x1conv(512->2048) -> BN -> LIF -> 1x1conv(2048->512) -> BN -> +x
// T=4 B=32 C=512 Ch=2048 HW=196. Split-hi/lo bf16 W1 (fp32-exact spike
// decisions), plain bf16 W2. R4 = R3 with the compile fix (helper hoisted):
// gemm1 deep pipeline with correct 3-4-phase wait depth; gemm2 reverted to
// proven r1 shallow structure; XCD-aware block swizzle on both GEMMs.

typedef __bf16 bf16x8 __attribute__((ext_vector_type(8)));
typedef float f32x4 __attribute__((ext_vector_type(4)));
typedef float f32x2 __attribute__((ext_vector_type(2)));

#define TPLANE 3211264u     // B*C*HW
#define NCOL   6272u        // B*HW
#define MFMA_BF16 __builtin_amdgcn_mfma_f32_16x16x32_bf16

#define BAR()  __builtin_amdgcn_s_barrier()
#define BARL() do { __builtin_amdgcn_s_barrier(); \
                    asm volatile("s_waitcnt lgkmcnt(0)" ::: "memory"); } while (0)
#define VMW(n) asm volatile("s_waitcnt vmcnt(" #n ")" ::: "memory")

static __device__ __forceinline__ uint16_t f2bf(float f) {
  union { float f; uint32_t u; } v; v.f = f;
  return (uint16_t)((v.u + 0x7FFFu + ((v.u >> 16) & 1u)) >> 16);  // RNE
}
static __device__ __forceinline__ float bf2f(uint16_t h) {
  union { uint32_t u; float f; } v; v.u = ((uint32_t)h) << 16;
  return v.f;
}
static __device__ __forceinline__ void async16(const void* g, void* l) {
  __builtin_amdgcn_global_load_lds((const __attribute__((address_space(1))) uint32_t*)g,
                                   (__attribute__((address_space(3))) uint32_t*)l, 16, 0, 0);
}
static __device__ __forceinline__ uint32_t bRd_g2(uint32_t g, uint32_t wn, uint32_t il) {
  return g * 4096u + wn * 1024u + il * 16u;
}

// ---------------------------------------------------------------------------
__global__ void prep_kernel(const float* __restrict__ W1, const float* __restrict__ W2,
                            const float* __restrict__ g1, const float* __restrict__ b1,
                            const float* __restrict__ m1, const float* __restrict__ v1,
                            const float* __restrict__ g2, const float* __restrict__ b2,
                            const float* __restrict__ m2, const float* __restrict__ v2,
                            uint16_t* __restrict__ Ws, uint16_t* __restrict__ W2b,
                            float* __restrict__ scale1, float* __restrict__ bias1,
                            float* __restrict__ scale2, float* __restrict__ bias2) {
  uint32_t i = blockIdx.x * 512u + threadIdx.x;
  uint32_t o = i >> 9, c = i & 511u;
  float w = W1[i];
  uint16_t hi = f2bf(w);
  uint16_t lo = f2bf(w - bf2f(hi));
  Ws[(size_t)(2u * o) * 512u + c] = hi;
  Ws[(size_t)(2u * o + 1u) * 512u + c] = lo;
  W2b[i] = f2bf(W2[i]);
  if (i < 2048u) { float s = g1[i] / sqrtf(v1[i] + 1e-5f); scale1[i] = s; bias1[i] = b1[i] - m1[i] * s; }
  if (i < 512u)  { float s = g2[i] / sqrtf(v2[i] + 1e-5f); scale2[i] = s; bias2[i] = b2[i] - m2[i] * s; }
}

// ---------------------------------------------------------------------------
// LIF over input (bit-exact fp32), spikes bf16 in K-blocked layout:
// chunk = (cblk*4 + t)*NCOL + n, 16B per chunk (8 channels).
__global__ void lif1_kernel(const float* __restrict__ x, uint16_t* __restrict__ s1) {
  __shared__ __align__(16) uint16_t sl[64 * 66 * 4];
  const uint32_t tid = threadIdx.x;
  const uint32_t c0 = blockIdx.x * 64u;
  const uint32_t n0 = blockIdx.y * 64u;
  #pragma unroll
  for (int j = 0; j < 16; ++j) {
    uint32_t idx = (uint32_t)j * 256u + tid;
    uint32_t cl = idx >> 6, nl = idx & 63u;
    uint32_t n = n0 + nl;
    uint32_t b = n / 196u, hw = n - b * 196u;
    const float* px = x + (size_t)(b * 512u + c0 + cl) * 196u + hw;
    float v = 0.f;
    uint16_t sp[4];
    #pragma unroll
    for (int t = 0; t < 4; ++t) {
      float xv = px[(size_t)t * TPLANE];
      v += (xv - v) * 0.5f;
      bool s = (v >= 1.0f);
      sp[t] = s ? (uint16_t)0x3F80u : (uint16_t)0u;
      v = s ? 0.f : v;
    }
    uint2 pk;
    pk.x = (uint32_t)sp[0] | ((uint32_t)sp[1] << 16);
    pk.y = (uint32_t)sp[2] | ((uint32_t)sp[3] << 16);
    *(uint2*)&sl[(cl * 66u + nl) * 4u] = pk;
  }
  __syncthreads();
  #pragma unroll
  for (int j = 0; j < 8; ++j) {
    uint32_t id = (uint32_t)j * 256u + tid;
    uint32_t nl = id & 63u, t = (id >> 6) & 3u, cb = id >> 8;
    uint32_t us[4];
    #pragma unroll
    for (int e = 0; e < 4; ++e) {
      uint32_t lo16 = sl[((cb * 8u + 2u * e) * 66u + nl) * 4u + t];
      uint32_t hi16 = sl[((cb * 8u + 2u * e + 1u) * 66u + nl) * 4u + t];
      us[e] = lo16 | (hi16 << 16);
    }
    uint32_t chunk = (((c0 >> 3) + cb) * 4u + t) * NCOL + n0 + nl;
    uint4 o4; o4.x = us[0]; o4.y = us[1]; o4.z = us[2]; o4.w = us[3];
    *(uint4*)(s1 + (size_t)chunk * 8u) = o4;
  }
}

// ---------------------------------------------------------------------------
// GEMM1: M'=4096 (hi/lo rows), K=512 (8 K-tiles of 64), N-strip 64n x 4t.
// 256x256 tile, 8 waves, dbuf 128KB LDS. Per K-tile 4 phases; stage issues
// q0:A0A2 q1:B0B1 q2:A1A3 q3:B2B3; waits VMW(4) placed after MFMA before the
// closing barrier => every load has 3-4 phases of cover.
__launch_bounds__(512, 2)
__global__ void gemm1_lif2_kernel(const uint16_t* __restrict__ Ws,
                                  const uint16_t* __restrict__ s1,
                                  const float* __restrict__ scale1,
                                  const float* __restrict__ bias1,
                                  uint16_t* __restrict__ s2) {
  extern __shared__ __align__(16) char lds[];   // [buf:2][A 32KB][B 32KB]
  const uint32_t tid = threadIdx.x;
  const uint32_t wid = tid >> 6, lane = tid & 63u;
  const uint32_t il = lane & 15u, g = lane >> 4;
  const uint32_t wm = wid >> 2, wn = wid & 3u;
  // XCD swizzle: 1568 blocks = 8 XCD x 196 contiguous chunks
  const uint32_t bid = blockIdx.x;
  const uint32_t lid = (bid & 7u) * 196u + (bid >> 3);
  const uint32_t m0 = (lid & 15u) * 256u;
  const uint32_t n0 = (lid >> 4) * 64u;
  const char* WsC = (const char*)Ws;
  const char* s1C = (const char*)s1;

  // staging lane constants (verified in r2): A chunks [i:256][q:8], src pre-swizzled
  const uint32_t ia = tid >> 3;
  const uint32_t qg = (tid & 7u) ^ (ia & 7u);
  const uint32_t aSrc = (m0 + ia) * 1024u + qg * 16u;
  // B chunks [kb:8][n4:4][t:4][nl:16]
  const uint32_t kbl = tid >> 8, colb = tid & 255u;
  const uint32_t bn4 = colb >> 6, bt = (colb >> 4) & 3u, bnl = colb & 15u;
  const uint32_t bSrc = ((kbl * 4u + bt) * NCOL + n0 + bn4 * 16u + bnl) * 16u;

  // ds-read lane constants (verified in r2, zero bank conflicts)
  const uint32_t aRd = (wm * 128u + il) * 128u + ((g ^ (il & 7u)) * 16u);
  const uint32_t bRd = g * 4096u + wn * 1024u + il * 16u;

  f32x4 acc[8][4];
  #pragma unroll
  for (int i = 0; i < 8; ++i)
    #pragma unroll
    for (int j = 0; j < 4; ++j) acc[i][j] = (f32x4){0.f, 0.f, 0.f, 0.f};
  bf16x8 af[4], bf[4];

#define SA1(ga, kn, bufo) async16(WsC + (aSrc + (ga)*65536u + (kn)*128u), \
      lds + (bufo) + (ga)*8192u + wid*1024u)
#define SB1(gb, kn, bufo) async16(s1C + (bSrc + (gb)*802816u + (kn)*3211264u), \
      lds + (bufo) + 32768u + (gb)*8192u + wid*1024u)
#define RDA1(fg, ks) do { _Pragma("unroll") for (int j = 0; j < 4; ++j) \
    af[j] = *(const bf16x8*)(Ac + ((aRd ^ ((ks) << 6)) + ((fg)*4u + (uint32_t)j) * 2048u)); } while (0)
#define RDB1(ks) do { _Pragma("unroll") for (int t = 0; t < 4; ++t) \
    bf[t] = *(const bf16x8*)(Bc + (bRd + (ks)*16384u + (uint32_t)t * 256u)); } while (0)
#define MF1(fg) do { __builtin_amdgcn_s_setprio(1); \
  _Pragma("unroll") for (int j = 0; j < 4; ++j) \
    _Pragma("unroll") for (int t = 0; t < 4; ++t) \
      acc[(fg)*4 + j][t] = MFMA_BF16(af[j], bf[t], acc[(fg)*4 + j][t], 0, 0, 0); \
  __builtin_amdgcn_s_setprio(0); } while (0)

  // prologue: tile0 in consumption order, then retire first 4 groups
  SA1(0, 0u, 0u); SA1(2, 0u, 0u); SB1(0, 0u, 0u); SB1(1, 0u, 0u);
  SA1(1, 0u, 0u); SA1(3, 0u, 0u); SB1(2, 0u, 0u); SB1(3, 0u, 0u);
  VMW(4);
  BAR();

  for (uint32_t kt = 0; kt < 7u; ++kt) {
    const uint32_t cur = kt & 1u;
    const uint32_t nb = (cur ^ 1u) * 65536u;
    const uint32_t kn = kt + 1u;
    const char* Ac = lds + cur * 65536u;
    const char* Bc = Ac + 32768u;
    // q0: fm0-3 x ks0
    RDA1(0u, 0u); RDB1(0u);
    SA1(0, kn, nb); SA1(2, kn, nb);
    BARL(); MF1(0); VMW(4); BAR();
    // q1: fm4-7 x ks0 (B regs persist)
    RDA1(1u, 0u);
    SB1(0, kn, nb); SB1(1, kn, nb);
    BARL(); MF1(1); VMW(4); BAR();
    // q2: fm0-3 x ks1
    RDA1(0u, 1u); RDB1(1u);
    SA1(1, kn, nb); SA1(3, kn, nb);
    BARL(); MF1(0); BAR();
    // q3: fm4-7 x ks1
    RDA1(1u, 1u);
    SB1(2, kn, nb); SB1(3, kn, nb);
    BARL(); MF1(1); VMW(4); BAR();
  }
  { // drain: kt=7, buffer 1, no issues
    const char* Ac = lds + 65536u;
    const char* Bc = Ac + 32768u;
    RDA1(0u, 0u); RDB1(0u); BARL(); MF1(0); VMW(2); BAR();
    RDA1(1u, 0u);           BARL(); MF1(1); VMW(0); BAR();
    RDA1(0u, 1u); RDB1(1u); BARL(); MF1(0); BAR();
    RDA1(1u, 1u);           BARL(); MF1(1);
  }
#undef SA1
#undef SB1
#undef RDA1
#undef RDB1
#undef MF1

  // epilogue: hi+lo combine, BN1, in-register LIF2 scan, scatter s2 (verified r2)
  const uint32_t n = n0 + wn * 16u + il;
  #pragma unroll
  for (int fm = 0; fm < 8; ++fm) {
    uint32_t oo = (m0 >> 1) + wm * 64u + (uint32_t)fm * 8u + 2u * g;
    f32x2 sc = *(const f32x2*)&scale1[oo];
    f32x2 bi = *(const f32x2*)&bias1[oo];
    float v0 = 0.f, v1 = 0.f;
    uint32_t outw[4];
    #pragma unroll
    for (int t = 0; t < 4; ++t) {
      float hb0 = (acc[fm][t][0] + acc[fm][t][1]) * sc[0] + bi[0];
      float hb1 = (acc[fm][t][2] + acc[fm][t][3]) * sc[1] + bi[1];
      v0 += (hb0 - v0) * 0.5f; bool s0 = (v0 >= 1.0f); v0 = s0 ? 0.f : v0;
      v1 += (hb1 - v1) * 0.5f; bool s1v = (v1 >= 1.0f); v1 = s1v ? 0.f : v1;
      outw[t] = (s0 ? 0x3F80u : 0u) | (s1v ? 0x3F800000u : 0u);
    }
    #pragma unroll
    for (int t = 0; t < 4; ++t) {
      size_t off = (size_t)(((oo >> 3) * 4u + (uint32_t)t) * NCOL + n) * 16u + (size_t)((oo & 7u) * 2u);
      *(uint32_t*)((char*)s2 + off) = outw[t];
    }
  }
}

// ---------------------------------------------------------------------------
// GEMM2 (proven r1 shallow structure): M=512, K=2048, 128M x (64n x 4t) tile,
// 48KB static LDS (3 blocks/CU), fused BN2 + residual + LDS-transpose
// float4 stores. + XCD swizzle (392 = 8x49).
__launch_bounds__(512)
__global__ void gemm2_out_kernel(const uint16_t* __restrict__ W2b,
                                 const uint16_t* __restrict__ s2,
                                 const float* __restrict__ scale2,
                                 const float* __restrict__ bias2,
                                 const float* __restrict__ xin,
                                 float* __restrict__ outp) {
  __shared__ __align__(16) char lds[49152];
  char* ldsA = lds;
  char* ldsB = lds + 16384;
  float* ep = (float*)lds;
  const uint32_t tid = threadIdx.x;
  const uint32_t wid = tid >> 6;
  const uint32_t lane = tid & 63u;
  const uint32_t il = lane & 15u, g = lane >> 4;
  const uint32_t wm = wid >> 2, wn = wid & 3u;
  const uint32_t bid = blockIdx.x;
  const uint32_t lid = (bid & 7u) * 49u + (bid >> 3);
  const uint32_t m0 = (lid & 3u) * 128u;
  const uint32_t n0 = (lid >> 2) * 64u;

  f32x4 acc[4][4];
  #pragma unroll
  for (int i = 0; i < 4; ++i)
    #pragma unroll
    for (int j = 0; j < 4; ++j) acc[i][j] = (f32x4){0.f, 0.f, 0.f, 0.f};

  for (int kt = 0; kt < 32; ++kt) {
    const uint32_t k0 = (uint32_t)kt * 64u;
    #pragma unroll
    for (uint32_t r = 0; r < 2; ++r) {
      uint32_t cid = r * 512u + tid;
      uint32_t i = cid >> 3, q = cid & 7u;
      const char* src = (const char*)W2b + (size_t)(m0 + i) * 4096u + (size_t)k0 * 2u
                        + (size_t)((q ^ (i & 7u)) * 16u);
      async16(src, ldsA + (r * 512u + wid * 64u) * 16u);
    }
    #pragma unroll
    for (uint32_t r = 0; r < 4; ++r) {
      uint32_t cid = r * 512u + tid;
      uint32_t kb = cid >> 8, rem = cid & 255u;
      uint32_t tt = rem >> 6, dn = rem & 63u;
      const char* src = (const char*)s2
          + (size_t)((((k0 >> 3) + kb) * 4u + tt) * NCOL + n0 + dn) * 16u;
      async16(src, ldsB + (r * 512u + wid * 64u) * 16u);
    }
    __syncthreads();
    #pragma unroll
    for (int ks = 0; ks < 2; ++ks) {
      bf16x8 af[4], bfr0, bfr1;
      #pragma unroll
      for (int th = 0; th < 2; ++th) {
        #pragma unroll
        for (int fm = 0; fm < 4; ++fm) {
          uint32_t i = wm * 64u + (uint32_t)fm * 16u + il;
          uint32_t q = (uint32_t)ks * 4u + g;
          af[fm] = *(const bf16x8*)(ldsA + (i * 8u + (q ^ (i & 7u))) * 16u);
        }
        uint32_t ch = bRd_g2(g, wn, il) + (uint32_t)th * 512u + (uint32_t)ks * 16384u;
        bfr0 = *(const bf16x8*)(ldsB + ch);
        bfr1 = *(const bf16x8*)(ldsB + ch + 256u);
        #pragma unroll
        for (int fm = 0; fm < 4; ++fm) {
          acc[fm][th*2]   = MFMA_BF16(af[fm], bfr0, acc[fm][th*2], 0, 0, 0);
          acc[fm][th*2+1] = MFMA_BF16(af[fm], bfr1, acc[fm][th*2+1], 0, 0, 0);
        }
      }
    }
    __syncthreads();
  }

  // epilogue: BN2 + residual, LDS transpose -> float4 stores
  const uint32_t cl = lane >> 2, qq = lane & 3u;
  #pragma unroll
  for (int fm = 0; fm < 4; ++fm) {
    const uint32_t cbase = m0 + wm * 64u + (uint32_t)fm * 16u;
    f32x4 sc = *(const f32x4*)&scale2[cbase + 4u * g];
    f32x4 bi = *(const f32x4*)&bias2[cbase + 4u * g];
    #pragma unroll
    for (int t = 0; t < 4; ++t)
      #pragma unroll
      for (int r = 0; r < 4; ++r)
        ep[wid * 1280u + ((4u * g + (uint32_t)r) * 4u + (uint32_t)t) * 20u + il]
            = acc[fm][t][r] * sc[r] + bi[r];
    __syncthreads();
    #pragma unroll
    for (int t = 0; t < 4; ++t) {
      f32x4 val = *(const f32x4*)&ep[wid * 1280u + (cl * 4u + (uint32_t)t) * 20u + qq * 4u];
      uint32_t nn = n0 + wn * 16u + qq * 4u;
      uint32_t b = nn / 196u, hw = nn - b * 196u;
      uint32_t c = cbase + cl;
      size_t off = (((size_t)t * 32u + b) * 512u + c) * 196u + hw;
      f32x4 iv = *(const f32x4*)(xin + off);
      *(f32x4*)(outp + off) = val + iv;
    }
    __syncthreads();
  }
}

// ---------------------------------------------------------------------------
extern "C" void kernel_launch(void* const* d_in, const int* in_sizes, int n_in,
                              void* d_out, int out_size, void* d_ws, size_t ws_size,
                              hipStream_t stream) {
  const float* x  = (const float*)d_in[0];
  const float* W1 = (const float*)d_in[1];
  const float* g1 = (const float*)d_in[2];
  const float* b1 = (const float*)d_in[3];
  const float* m1 = (const float*)d_in[4];
  const float* v1 = (const float*)d_in[5];
  const float* W2 = (const float*)d_in[6];
  const float* g2 = (const float*)d_in[7];
  const float* b2 = (const float*)d_in[8];
  const float* m2 = (const float*)d_in[9];
  const float* v2 = (const float*)d_in[10];
  float* out = (float*)d_out;
  char* ws = (char*)d_ws;

  uint16_t* s2b    = (uint16_t*)(ws);                    // 102,760,448 B
  uint16_t* s1b    = (uint16_t*)(ws + 102760448);        //  25,690,112 B
  uint16_t* Wsb    = (uint16_t*)(ws + 128450560);        //   4,194,304 B
  uint16_t* W2bb   = (uint16_t*)(ws + 132644864);        //   2,097,152 B
  float*    scale1 = (float*)(ws + 134742016);
  float*    bias1  = (float*)(ws + 134750208);
  float*    scale2 = (float*)(ws + 134758400);
  float*    bias2  = (float*)(ws + 134760448);

  (void)hipFuncSetAttribute((const void*)gemm1_lif2_kernel,
                            hipFuncAttributeMaxDynamicSharedMemorySize, 131072);

  prep_kernel<<<2048, 512, 0, stream>>>(W1, W2, g1, b1, m1, v1, g2, b2, m2, v2,
                                        Wsb, W2bb, scale1, bias1, scale2, bias2);
  lif1_kernel<<<dim3(8, 98), 256, 0, stream>>>(x, s1b);
  gemm1_lif2_kernel<<<1568, 512, 131072, stream>>>(Wsb, s1b, scale1, bias1, s2b);
  gemm2_out_kernel<<<392, 512, 0, stream>>>(W2bb, s2b, scale2, bias2, x, out);
}

// Round 5
// 139.317 us; speedup vs baseline: 1.6050x; 1.4490x over previous
//
#include <hip/hip_runtime.h>
#include <stdint.h>

// LIF -> 1x1conv(512->2048) -> BN -> LIF -> 1x1conv(2048->512) -> BN -> +x
// T=4 B=32 C=512 Ch=2048 HW=196.
// R5: GEMM1 single-pass fp16 W1 (halves MFMA work vs hi/lo bf16 split;
// error ~7e-5 keeps LIF2 spike decisions intact), R1-proven shallow
// 2-barrier structure + XCD swizzle. GEMM2 unchanged (proven, bf16 W2).

typedef __bf16 bf16x8 __attribute__((ext_vector_type(8)));
typedef _Float16 f16x8 __attribute__((ext_vector_type(8)));
typedef float f32x4 __attribute__((ext_vector_type(4)));

#define TPLANE 3211264u     // B*C*HW
#define NCOL   6272u        // B*HW
#define MFMA_BF16 __builtin_amdgcn_mfma_f32_16x16x32_bf16
#define MFMA_F16  __builtin_amdgcn_mfma_f32_16x16x32_f16

static __device__ __forceinline__ uint16_t f2bf(float f) {
  union { float f; uint32_t u; } v; v.f = f;
  return (uint16_t)((v.u + 0x7FFFu + ((v.u >> 16) & 1u)) >> 16);  // RNE
}
static __device__ __forceinline__ void async16(const void* g, void* l) {
  __builtin_amdgcn_global_load_lds((const __attribute__((address_space(1))) uint32_t*)g,
                                   (__attribute__((address_space(3))) uint32_t*)l, 16, 0, 0);
}
static __device__ __forceinline__ uint32_t bRd_g2(uint32_t g, uint32_t wn, uint32_t il) {
  return g * 4096u + wn * 1024u + il * 16u;
}

// ---------------------------------------------------------------------------
// prep: W1 -> fp16 [2048][512]; W2 -> bf16; BN constants folded.
__global__ void prep_kernel(const float* __restrict__ W1, const float* __restrict__ W2,
                            const float* __restrict__ g1, const float* __restrict__ b1,
                            const float* __restrict__ m1, const float* __restrict__ v1,
                            const float* __restrict__ g2, const float* __restrict__ b2,
                            const float* __restrict__ m2, const float* __restrict__ v2,
                            _Float16* __restrict__ W1h, uint16_t* __restrict__ W2b,
                            float* __restrict__ scale1, float* __restrict__ bias1,
                            float* __restrict__ scale2, float* __restrict__ bias2) {
  uint32_t i = blockIdx.x * 512u + threadIdx.x;   // 2048*512 threads
  W1h[i] = (_Float16)W1[i];
  W2b[i] = f2bf(W2[i]);
  if (i < 2048u) { float s = g1[i] / sqrtf(v1[i] + 1e-5f); scale1[i] = s; bias1[i] = b1[i] - m1[i] * s; }
  if (i < 512u)  { float s = g2[i] / sqrtf(v2[i] + 1e-5f); scale2[i] = s; bias2[i] = b2[i] - m2[i] * s; }
}

// ---------------------------------------------------------------------------
// LIF over input (bit-exact fp32), spikes fp16 (0x3C00) in K-blocked layout:
// chunk = (cblk*4 + t)*NCOL + n, 16B per chunk (8 channels).
__global__ void lif1_kernel(const float* __restrict__ x, uint16_t* __restrict__ s1) {
  __shared__ __align__(16) uint16_t sl[64 * 66 * 4];
  const uint32_t tid = threadIdx.x;
  const uint32_t c0 = blockIdx.x * 64u;
  const uint32_t n0 = blockIdx.y * 64u;
  #pragma unroll
  for (int j = 0; j < 16; ++j) {
    uint32_t idx = (uint32_t)j * 256u + tid;
    uint32_t cl = idx >> 6, nl = idx & 63u;
    uint32_t n = n0 + nl;
    uint32_t b = n / 196u, hw = n - b * 196u;
    const float* px = x + (size_t)(b * 512u + c0 + cl) * 196u + hw;
    float v = 0.f;
    uint16_t sp[4];
    #pragma unroll
    for (int t = 0; t < 4; ++t) {
      float xv = px[(size_t)t * TPLANE];
      v += (xv - v) * 0.5f;                // exact: *0.5 never rounds
      bool s = (v >= 1.0f);
      sp[t] = s ? (uint16_t)0x3C00u : (uint16_t)0u;   // fp16 1.0
      v = s ? 0.f : v;
    }
    uint2 pk;
    pk.x = (uint32_t)sp[0] | ((uint32_t)sp[1] << 16);
    pk.y = (uint32_t)sp[2] | ((uint32_t)sp[3] << 16);
    *(uint2*)&sl[(cl * 66u + nl) * 4u] = pk;
  }
  __syncthreads();
  #pragma unroll
  for (int j = 0; j < 8; ++j) {
    uint32_t id = (uint32_t)j * 256u + tid;
    uint32_t nl = id & 63u, t = (id >> 6) & 3u, cb = id >> 8;
    uint32_t us[4];
    #pragma unroll
    for (int e = 0; e < 4; ++e) {
      uint32_t lo16 = sl[((cb * 8u + 2u * e) * 66u + nl) * 4u + t];
      uint32_t hi16 = sl[((cb * 8u + 2u * e + 1u) * 66u + nl) * 4u + t];
      us[e] = lo16 | (hi16 << 16);
    }
    uint32_t chunk = (((c0 >> 3) + cb) * 4u + t) * NCOL + n0 + nl;
    uint4 o4; o4.x = us[0]; o4.y = us[1]; o4.z = us[2]; o4.w = us[3];
    *(uint4*)(s1 + (size_t)chunk * 8u) = o4;
  }
}

// ---------------------------------------------------------------------------
// GEMM1: M=2048 (fp16 W1), K=512, N-strip 64n x 4t. R1-proven shallow
// 2-barrier structure, 128M tile, 48KB static LDS, fused BN1 + in-register
// LIF2 scan -> s2 spikes (bf16). XCD swizzle over 1568 = 8x196 blocks.
__launch_bounds__(512)
__global__ void gemm1_lif2_kernel(const _Float16* __restrict__ W1h,
                                  const uint16_t* __restrict__ s1,
                                  const float* __restrict__ scale1,
                                  const float* __restrict__ bias1,
                                  uint16_t* __restrict__ s2) {
  __shared__ __align__(16) char lds[49152];
  char* ldsA = lds;               // 16KB: [i:128][q':8]*16B, q' = q ^ (i&7)
  char* ldsB = lds + 16384;       // 32KB: [kb:8][n4:4][t:4][nl:16]*16B
  const uint32_t tid = threadIdx.x;
  const uint32_t wid = tid >> 6;
  const uint32_t lane = tid & 63u;
  const uint32_t il = lane & 15u, g = lane >> 4;
  const uint32_t wm = wid >> 2, wn = wid & 3u;
  const uint32_t bid = blockIdx.x;
  const uint32_t lid = (bid & 7u) * 196u + (bid >> 3);   // 1568 = 8*196
  const uint32_t m0 = (lid & 15u) * 128u;                // 16 M-blocks
  const uint32_t n0 = (lid >> 4) * 64u;                  // 98 N-blocks

  f32x4 acc[4][4];                // [fm][t]
  #pragma unroll
  for (int i = 0; i < 4; ++i)
    #pragma unroll
    for (int j = 0; j < 4; ++j) acc[i][j] = (f32x4){0.f, 0.f, 0.f, 0.f};

  for (int kt = 0; kt < 8; ++kt) {
    const uint32_t k0 = (uint32_t)kt * 64u;
    #pragma unroll
    for (uint32_t r = 0; r < 2; ++r) {     // A tile: 1024 16B chunks
      uint32_t cid = r * 512u + tid;
      uint32_t i = cid >> 3, q = cid & 7u;
      const char* src = (const char*)W1h + (size_t)(m0 + i) * 1024u + (size_t)k0 * 2u
                        + (size_t)((q ^ (i & 7u)) * 16u);
      async16(src, ldsA + (r * 512u + wid * 64u) * 16u);
    }
    #pragma unroll
    for (uint32_t r = 0; r < 4; ++r) {     // B tile: 2048 16B chunks
      uint32_t cid = r * 512u + tid;
      uint32_t kb = cid >> 8, rem = cid & 255u;
      uint32_t tt = rem >> 6, dn = rem & 63u;
      const char* src = (const char*)s1
          + (size_t)((((k0 >> 3) + kb) * 4u + tt) * NCOL + n0 + dn) * 16u;
      async16(src, ldsB + (r * 512u + wid * 64u) * 16u);
    }
    __syncthreads();
    #pragma unroll
    for (int ks = 0; ks < 2; ++ks) {
      f16x8 af[4], bfr0, bfr1;
      #pragma unroll
      for (int th = 0; th < 2; ++th) {
        #pragma unroll
        for (int fm = 0; fm < 4; ++fm) {
          uint32_t i = wm * 64u + (uint32_t)fm * 16u + il;
          uint32_t q = (uint32_t)ks * 4u + g;
          af[fm] = *(const f16x8*)(ldsA + (i * 8u + (q ^ (i & 7u))) * 16u);
        }
        uint32_t ch = bRd_g2(g, wn, il) + (uint32_t)th * 512u + (uint32_t)ks * 16384u;
        bfr0 = *(const f16x8*)(ldsB + ch);
        bfr1 = *(const f16x8*)(ldsB + ch + 256u);
        #pragma unroll
        for (int fm = 0; fm < 4; ++fm) {
          acc[fm][th*2]   = MFMA_F16(af[fm], bfr0, acc[fm][th*2], 0, 0, 0);
          acc[fm][th*2+1] = MFMA_F16(af[fm], bfr1, acc[fm][th*2+1], 0, 0, 0);
        }
      }
    }
    __syncthreads();
  }

  // epilogue: BN1 + in-register LIF2 scan; lane holds 4 consecutive channels
  // ch0 = m0 + wm*64 + fm*16 + 4g (C/D row = 4g + r), col n = n0 + wn*16 + il.
  const uint32_t n = n0 + wn * 16u + il;
  #pragma unroll
  for (int fm = 0; fm < 4; ++fm) {
    const uint32_t ch0 = m0 + wm * 64u + (uint32_t)fm * 16u + 4u * g;
    f32x4 sc = *(const f32x4*)&scale1[ch0];
    f32x4 bi = *(const f32x4*)&bias1[ch0];
    float v0 = 0.f, v1 = 0.f, v2 = 0.f, v3 = 0.f;
    #pragma unroll
    for (int t = 0; t < 4; ++t) {
      float h0 = acc[fm][t][0] * sc[0] + bi[0];
      float h1 = acc[fm][t][1] * sc[1] + bi[1];
      float h2 = acc[fm][t][2] * sc[2] + bi[2];
      float h3 = acc[fm][t][3] * sc[3] + bi[3];
      v0 += (h0 - v0) * 0.5f; bool s0 = (v0 >= 1.0f); v0 = s0 ? 0.f : v0;
      v1 += (h1 - v1) * 0.5f; bool s1v = (v1 >= 1.0f); v1 = s1v ? 0.f : v1;
      v2 += (h2 - v2) * 0.5f; bool s2v = (v2 >= 1.0f); v2 = s2v ? 0.f : v2;
      v3 += (h3 - v3) * 0.5f; bool s3v = (v3 >= 1.0f); v3 = s3v ? 0.f : v3;
      uint2 pk;
      pk.x = (s0 ? 0x3F80u : 0u) | (s1v ? 0x3F800000u : 0u);   // bf16 spikes
      pk.y = (s2v ? 0x3F80u : 0u) | (s3v ? 0x3F800000u : 0u);
      uint32_t chunk = ((ch0 >> 3) * 4u + (uint32_t)t) * NCOL + n;
      *(uint2*)((char*)s2 + (size_t)chunk * 16u + (size_t)((ch0 & 7u) * 2u)) = pk;
    }
  }
}

// ---------------------------------------------------------------------------
// GEMM2 (proven shallow): M=512, K=2048, 128M x (64n x 4t) tile, 48KB LDS,
// fused BN2 + residual + LDS-transpose float4 stores. XCD swizzle (392=8x49).
__launch_bounds__(512)
__global__ void gemm2_out_kernel(const uint16_t* __restrict__ W2b,
                                 const uint16_t* __restrict__ s2,
                                 const float* __restrict__ scale2,
                                 const float* __restrict__ bias2,
                                 const float* __restrict__ xin,
                                 float* __restrict__ outp) {
  __shared__ __align__(16) char lds[49152];
  char* ldsA = lds;
  char* ldsB = lds + 16384;
  float* ep = (float*)lds;
  const uint32_t tid = threadIdx.x;
  const uint32_t wid = tid >> 6;
  const uint32_t lane = tid & 63u;
  const uint32_t il = lane & 15u, g = lane >> 4;
  const uint32_t wm = wid >> 2, wn = wid & 3u;
  const uint32_t bid = blockIdx.x;
  const uint32_t lid = (bid & 7u) * 49u + (bid >> 3);
  const uint32_t m0 = (lid & 3u) * 128u;
  const uint32_t n0 = (lid >> 2) * 64u;

  f32x4 acc[4][4];
  #pragma unroll
  for (int i = 0; i < 4; ++i)
    #pragma unroll
    for (int j = 0; j < 4; ++j) acc[i][j] = (f32x4){0.f, 0.f, 0.f, 0.f};

  for (int kt = 0; kt < 32; ++kt) {
    const uint32_t k0 = (uint32_t)kt * 64u;
    #pragma unroll
    for (uint32_t r = 0; r < 2; ++r) {
      uint32_t cid = r * 512u + tid;
      uint32_t i = cid >> 3, q = cid & 7u;
      const char* src = (const char*)W2b + (size_t)(m0 + i) * 4096u + (size_t)k0 * 2u
                        + (size_t)((q ^ (i & 7u)) * 16u);
      async16(src, ldsA + (r * 512u + wid * 64u) * 16u);
    }
    #pragma unroll
    for (uint32_t r = 0; r < 4; ++r) {
      uint32_t cid = r * 512u + tid;
      uint32_t kb = cid >> 8, rem = cid & 255u;
      uint32_t tt = rem >> 6, dn = rem & 63u;
      const char* src = (const char*)s2
          + (size_t)((((k0 >> 3) + kb) * 4u + tt) * NCOL + n0 + dn) * 16u;
      async16(src, ldsB + (r * 512u + wid * 64u) * 16u);
    }
    __syncthreads();
    #pragma unroll
    for (int ks = 0; ks < 2; ++ks) {
      bf16x8 af[4], bfr0, bfr1;
      #pragma unroll
      for (int th = 0; th < 2; ++th) {
        #pragma unroll
        for (int fm = 0; fm < 4; ++fm) {
          uint32_t i = wm * 64u + (uint32_t)fm * 16u + il;
          uint32_t q = (uint32_t)ks * 4u + g;
          af[fm] = *(const bf16x8*)(ldsA + (i * 8u + (q ^ (i & 7u))) * 16u);
        }
        uint32_t ch = bRd_g2(g, wn, il) + (uint32_t)th * 512u + (uint32_t)ks * 16384u;
        bfr0 = *(const bf16x8*)(ldsB + ch);
        bfr1 = *(const bf16x8*)(ldsB + ch + 256u);
        #pragma unroll
        for (int fm = 0; fm < 4; ++fm) {
          acc[fm][th*2]   = MFMA_BF16(af[fm], bfr0, acc[fm][th*2], 0, 0, 0);
          acc[fm][th*2+1] = MFMA_BF16(af[fm], bfr1, acc[fm][th*2+1], 0, 0, 0);
        }
      }
    }
    __syncthreads();
  }

  // epilogue: BN2 + residual, LDS transpose -> float4 stores
  const uint32_t cl = lane >> 2, qq = lane & 3u;
  #pragma unroll
  for (int fm = 0; fm < 4; ++fm) {
    const uint32_t cbase = m0 + wm * 64u + (uint32_t)fm * 16u;
    f32x4 sc = *(const f32x4*)&scale2[cbase + 4u * g];
    f32x4 bi = *(const f32x4*)&bias2[cbase + 4u * g];
    #pragma unroll
    for (int t = 0; t < 4; ++t)
      #pragma unroll
      for (int r = 0; r < 4; ++r)
        ep[wid * 1280u + ((4u * g + (uint32_t)r) * 4u + (uint32_t)t) * 20u + il]
            = acc[fm][t][r] * sc[r] + bi[r];
    __syncthreads();
    #pragma unroll
    for (int t = 0; t < 4; ++t) {
      f32x4 val = *(const f32x4*)&ep[wid * 1280u + (cl * 4u + (uint32_t)t) * 20u + qq * 4u];
      uint32_t nn = n0 + wn * 16u + qq * 4u;
      uint32_t b = nn / 196u, hw = nn - b * 196u;
      uint32_t c = cbase + cl;
      size_t off = (((size_t)t * 32u + b) * 512u + c) * 196u + hw;
      f32x4 iv = *(const f32x4*)(xin + off);
      *(f32x4*)(outp + off) = val + iv;
    }
    __syncthreads();
  }
}

// ---------------------------------------------------------------------------
extern "C" void kernel_launch(void* const* d_in, const int* in_sizes, int n_in,
                              void* d_out, int out_size, void* d_ws, size_t ws_size,
                              hipStream_t stream) {
  const float* x  = (const float*)d_in[0];
  const float* W1 = (const float*)d_in[1];
  const float* g1 = (const float*)d_in[2];
  const float* b1 = (const float*)d_in[3];
  const float* m1 = (const float*)d_in[4];
  const float* v1 = (const float*)d_in[5];
  const float* W2 = (const float*)d_in[6];
  const float* g2 = (const float*)d_in[7];
  const float* b2 = (const float*)d_in[8];
  const float* m2 = (const float*)d_in[9];
  const float* v2 = (const float*)d_in[10];
  float* out = (float*)d_out;
  char* ws = (char*)d_ws;

  uint16_t*  s2b    = (uint16_t*)(ws);                    // 102,760,448 B  [256][4][6272][8] bf16
  uint16_t*  s1b    = (uint16_t*)(ws + 102760448);        //  25,690,112 B  [64][4][6272][8] fp16
  _Float16*  W1h    = (_Float16*)(ws + 128450560);        //   2,097,152 B  [2048][512] fp16
  uint16_t*  W2bb   = (uint16_t*)(ws + 132644864);        //   2,097,152 B  [512][2048] bf16
  float*     scale1 = (float*)(ws + 134742016);
  float*     bias1  = (float*)(ws + 134750208);
  float*     scale2 = (float*)(ws + 134758400);
  float*     bias2  = (float*)(ws + 134760448);

  prep_kernel<<<2048, 512, 0, stream>>>(W1, W2, g1, b1, m1, v1, g2, b2, m2, v2,
                                        W1h, W2bb, scale1, bias1, scale2, bias2);
  lif1_kernel<<<dim3(8, 98), 256, 0, stream>>>(x, s1b);
  gemm1_lif2_kernel<<<1568, 512, 0, stream>>>(W1h, s1b, scale1, bias1, s2b);
  gemm2_out_kernel<<<392, 512, 0, stream>>>(W2bb, s2b, scale2, bias2, x, out);
}